// Round 1
// baseline (285.543 us; speedup 1.0000x reference)
//
#include <hip/hip_runtime.h>
#include <hip/hip_bf16.h>
#include <stdint.h>

typedef unsigned short u16;
typedef unsigned int u32;
typedef __attribute__((ext_vector_type(8))) __bf16 bfrag;
typedef __attribute__((ext_vector_type(4))) float f32x4;
typedef __attribute__((ext_vector_type(4))) unsigned short u16x4;

__device__ __forceinline__ u16 f2bf(float f){
  union { float f; u32 u; } v; v.f = f;
  u32 u = v.u;
  return (u16)((u + 0x7fffu + ((u >> 16) & 1u)) >> 16);
}

__device__ __forceinline__ void gload_lds16(const void* g, void* l){
  __builtin_amdgcn_global_load_lds(
      (__attribute__((address_space(1))) void*)(unsigned long long)g,
      (__attribute__((address_space(3))) void*)(u32)(unsigned long long)l,
      16, 0, 0);
}

// ---------------- converts ----------------
__global__ void __launch_bounds__(256) k_cvt(const float* __restrict__ s, u16* __restrict__ d, int n4){
  int i = blockIdx.x*256 + threadIdx.x;
  if (i >= n4) return;
  float4 v = ((const float4*)s)[i];
  u16x4 o; o[0]=f2bf(v.x); o[1]=f2bf(v.y); o[2]=f2bf(v.z); o[3]=f2bf(v.w);
  ((u16x4*)d)[i] = o;
}

// past_k/past_v [16][3072][128] f32 -> [16][4096][128] bf16 (rows 0..3071)
__global__ void __launch_bounds__(256) k_cvt_past(const float* __restrict__ s, u16* __restrict__ d, int n4){
  int i = blockIdx.x*256 + threadIdx.x;
  if (i >= n4) return;
  int e = i*4;
  int row = e >> 7;
  int col = e & 127;
  int bh = row / 3072;
  int m = row - bh*3072;
  float4 v = ((const float4*)s)[i];
  u16x4 o; o[0]=f2bf(v.x); o[1]=f2bf(v.y); o[2]=f2bf(v.z); o[3]=f2bf(v.w);
  *(u16x4*)(d + ((size_t)(bh*4096 + m) << 7) + col) = o;
}

// ---------------- GEMM C[M][N] = A[M][K] * B[N][K]^T ----------------
// EPI=0: bf16 out; EPI=1: f32 out + bias
template<int EPI>
__global__ void __launch_bounds__(256) k_gemm(
    const u16* __restrict__ A, const u16* __restrict__ Bm,
    u16* __restrict__ Cb, float* __restrict__ Cf, const float* __restrict__ bias,
    int M, int Nn, int K)
{
  __shared__ u16 lsA[2][4096];
  __shared__ u16 lsB[2][4096];
  const int t = threadIdx.x, lane = t & 63, wid = t >> 6;
  const int l15 = lane & 15, l4 = lane >> 4;
  const int wm = wid >> 1, wn = wid & 1;
  const int bn = blockIdx.x, bm = blockIdx.y;
  const u16* Ab = A + (size_t)bm*128*K;
  const u16* Bb = Bm + (size_t)bn*128*K;

  auto stage = [&](u16* ls, const u16* g, int kof){
    #pragma unroll
    for (int r = 0; r < 2; ++r){
      int row = r*64 + (t >> 2);
      int s = (t & 3) ^ ((row >> 1) & 3);   // pre-swizzle source so swizzled LDS is linear-written
      gload_lds16(g + (size_t)row*K + kof + s*8, ls + r*2048 + wid*512);
    }
  };

  f32x4 acc[4][4] = {};
  stage(&lsA[0][0], Ab, 0);
  stage(&lsB[0][0], Bb, 0);
  const int NT = K >> 5;
  const int sl = l4 ^ ((l15 >> 1) & 3);
  const int ra0 = wm*64 + l15, rb0 = wn*64 + l15;
  for (int kt = 0; kt < NT; ++kt){
    __syncthreads();
    const int cur = kt & 1;
    if (kt + 1 < NT){
      stage(&lsA[cur ^ 1][0], Ab, (kt + 1)*32);
      stage(&lsB[cur ^ 1][0], Bb, (kt + 1)*32);
    }
    bfrag af[4], bfv[4];
    #pragma unroll
    for (int i = 0; i < 4; ++i){
      af[i]  = *(const bfrag*)&lsA[cur][(ra0 + i*16)*32 + sl*8];
      bfv[i] = *(const bfrag*)&lsB[cur][(rb0 + i*16)*32 + sl*8];
    }
    #pragma unroll
    for (int i = 0; i < 4; ++i)
      #pragma unroll
      for (int j = 0; j < 4; ++j)
        acc[i][j] = __builtin_amdgcn_mfma_f32_16x16x32_bf16(af[i], bfv[j], acc[i][j], 0, 0, 0);
  }
  const int row0 = bm*128 + wm*64, col0 = bn*128 + wn*64;
  #pragma unroll
  for (int i = 0; i < 4; ++i)
    #pragma unroll
    for (int j = 0; j < 4; ++j){
      int cc = col0 + j*16 + l15;
      float bv = (EPI == 1) ? bias[cc] : 0.f;
      #pragma unroll
      for (int r = 0; r < 4; ++r){
        int rr = row0 + i*16 + l4*4 + r;
        if (EPI == 0) Cb[(size_t)rr*Nn + cc] = f2bf(acc[i][j][r]);
        else          Cf[(size_t)rr*Nn + cc] = acc[i][j][r] + bv;
      }
    }
}

// ---------------- fused RMSNorm + RoPE + scatter ----------------
// proj [4096][3072] bf16; chunks: 0..15 q heads, 16..19 k heads, 20..23 v heads
__global__ void __launch_bounds__(256) k_rmsrope(
    const u16* __restrict__ proj, const float* __restrict__ cosb, const float* __restrict__ sinb,
    const float* __restrict__ wq, const float* __restrict__ wk,
    u16* __restrict__ q_ro, u16* __restrict__ k_all, u16* __restrict__ v_all)
{
  const int bn = blockIdx.x;
  const int b = bn >> 10, n = bn & 1023;
  const int lane = threadIdx.x & 63, w = threadIdx.x >> 6;
  const int chunk = blockIdx.y*4 + w;
  const u16* src = proj + (size_t)bn*3072 + chunk*128 + lane*2;
  const u32 raw = *(const u32*)src;
  union { u32 u; float f; } a, c2;
  a.u = raw << 16; c2.u = raw & 0xffff0000u;
  float x0 = a.f, x1 = c2.f;
  if (chunk >= 20){
    int hk = chunk - 20;
    *(u32*)(v_all + (((size_t)(b*4 + hk)*4096 + 3072 + n) << 7) + lane*2) = raw;
    return;
  }
  float ss = x0*x0 + x1*x1;
  #pragma unroll
  for (int m = 1; m < 64; m <<= 1) ss += __shfl_xor(ss, m, 64);
  float inv = rsqrtf(ss*(1.f/128.f) + 1e-6f);
  const float* wn2 = (chunk < 16) ? wq : wk;
  x0 *= inv*wn2[lane*2]; x1 *= inv*wn2[lane*2 + 1];
  float cz = cosb[n*64 + lane], sz = sinb[n*64 + lane];
  float r0 = x0*cz - x1*sz;
  float r1 = x0*sz + x1*cz;
  u32 outp = (u32)f2bf(r0) | ((u32)f2bf(r1) << 16);
  if (chunk < 16){
    *(u32*)(q_ro + (((size_t)(b*16 + chunk)*1024 + n) << 7) + lane*2) = outp;
  } else {
    int hk = chunk - 16;
    *(u32*)(k_all + (((size_t)(b*4 + hk)*4096 + 3072 + n) << 7) + lane*2) = outp;
  }
}

// ---------------- V transpose: v_all[pl][m][d] -> v_t[pl][d][m] ----------------
__global__ void __launch_bounds__(256) k_transpose_v(const u16* __restrict__ v_all, u16* __restrict__ v_t){
  __shared__ u16 T[64][65];
  const int mt = blockIdx.x, dt = blockIdx.y, pl = blockIdx.z;
  const u16* src = v_all + (size_t)pl*4096*128 + (size_t)mt*64*128 + dt*64;
  u16* dst = v_t + (size_t)pl*128*4096 + (size_t)dt*64*4096 + mt*64;
  const int t = threadIdx.x;
  #pragma unroll
  for (int r = 0; r < 2; ++r){
    int row = r*32 + (t >> 3);
    int c8 = (t & 7)*8;
    bfrag v = *(const bfrag*)(src + (size_t)row*128 + c8);
    union { bfrag v; u16 e[8]; } uv; uv.v = v;
    #pragma unroll
    for (int j = 0; j < 8; ++j) T[row][c8 + j] = uv.e[j];
  }
  __syncthreads();
  #pragma unroll
  for (int r = 0; r < 2; ++r){
    int drow = r*32 + (t >> 3);
    int m8 = (t & 7)*8;
    union { bfrag v; u16 e[8]; } uv;
    #pragma unroll
    for (int j = 0; j < 8; ++j) uv.e[j] = T[m8 + j][drow];
    *(bfrag*)(dst + (size_t)drow*4096 + m8) = uv.v;
  }
}

// ---------------- flash attention, swapped QK^T, GQA block ----------------
// grid 256: block = (b, hk, 64-query tile); 8 waves: wave = (head in group, 32-q half)
__global__ void __launch_bounds__(512) k_attn(
    const u16* __restrict__ q_ro, const u16* __restrict__ k_all,
    const u16* __restrict__ v_t, u16* __restrict__ attn_o)
{
  __shared__ u16 Kl[2][64*128];   // [k][d], slot^=(row&7) swizzled
  __shared__ u16 Vt[2][128*64];   // [d][k], slot^=(row&7) swizzled
  const int bid = blockIdx.x;
  const int qt = bid & 15, hk = (bid >> 4) & 3, b = bid >> 6;
  const int t = threadIdx.x, lane = t & 63, w = t >> 6;
  const int l15 = lane & 15, l4 = lane >> 4;
  const int h = hk*4 + (w >> 1);
  const int qbase = qt*64 + (w & 1)*32;

  const u16* qplane = q_ro + (size_t)(b*16 + h)*1024*128;
  const u16* kplane = k_all + (size_t)(b*4 + hk)*4096*128;
  const u16* vplane = v_t  + (size_t)(b*4 + hk)*128*4096;

  bfrag qf[2][4];
  #pragma unroll
  for (int qmi = 0; qmi < 2; ++qmi){
    const u16* qrow = qplane + (size_t)(qbase + qmi*16 + l15)*128;
    #pragma unroll
    for (int dks = 0; dks < 4; ++dks)
      qf[qmi][dks] = *(const bfrag*)(qrow + dks*32 + l4*8);
  }

  const int kb0 = qt*64 + 1024;
  auto stage = [&](int buf, int kb){
    #pragma unroll
    for (int r = 0; r < 2; ++r){
      int row = r*32 + (t >> 4);
      int s = (t & 15) ^ (row & 7);
      gload_lds16(kplane + (size_t)(kb + row)*128 + s*8, &Kl[buf][r*4096 + w*512]);
    }
    #pragma unroll
    for (int r = 0; r < 2; ++r){
      int row = r*64 + (t >> 3);
      int s = (t & 7) ^ (row & 7);
      gload_lds16(vplane + (size_t)row*4096 + kb + s*8, &Vt[buf][r*4096 + w*512]);
    }
  };

  f32x4 acc_o[8][2] = {};
  float m_run[2] = {-1e30f, -1e30f};
  float l_run[2] = {0.f, 0.f};
  const int qpos0 = 3072 + qbase + l15;
  const int qpmin = 3072 + qbase;
  const float sc = 0.08838834764831845f;

  stage(0, kb0);
  int cur = 0;
  for (int c = 0; c < 33; ++c){
    __syncthreads();
    const int kb = kb0 + c*64;
    if (c < 32) stage(cur ^ 1, kb + 64);

    // S^T[k][q] = K * Q^T
    f32x4 acc_s[4][2] = {};
    #pragma unroll
    for (int dks = 0; dks < 4; ++dks){
      bfrag kf[4];
      #pragma unroll
      for (int kni = 0; kni < 4; ++kni){
        int rk = kni*16 + l15;
        int slot = (dks*4 + l4) ^ (rk & 7);
        kf[kni] = *(const bfrag*)&Kl[cur][rk*128 + slot*8];
      }
      #pragma unroll
      for (int kni = 0; kni < 4; ++kni)
        #pragma unroll
        for (int qmi = 0; qmi < 2; ++qmi)
          acc_s[kni][qmi] = __builtin_amdgcn_mfma_f32_16x16x32_bf16(kf[kni], qf[qmi][dks], acc_s[kni][qmi], 0, 0, 0);
    }

    const bool full = (kb >= qpmin - 2016) && (kb + 63 <= qpmin);
    #pragma unroll
    for (int kni = 0; kni < 4; ++kni)
      #pragma unroll
      for (int qmi = 0; qmi < 2; ++qmi)
        #pragma unroll
        for (int r = 0; r < 4; ++r){
          float s = acc_s[kni][qmi][r]*sc;
          if (!full){
            int kpos = kb + kni*16 + l4*4 + r;
            int dq = (qpos0 + qmi*16) - kpos;
            if (dq < 0 || dq >= 2048) s = -__builtin_inff();
          }
          acc_s[kni][qmi][r] = s;
        }

    float ef[2];
    #pragma unroll
    for (int qmi = 0; qmi < 2; ++qmi){
      float mx = -__builtin_inff();
      #pragma unroll
      for (int kni = 0; kni < 4; ++kni)
        #pragma unroll
        for (int r = 0; r < 4; ++r) mx = fmaxf(mx, acc_s[kni][qmi][r]);
      mx = fmaxf(mx, __shfl_xor(mx, 16, 64));
      mx = fmaxf(mx, __shfl_xor(mx, 32, 64));
      float mnew = fmaxf(m_run[qmi], mx);
      ef[qmi] = __expf(m_run[qmi] - mnew);
      float ls = 0.f;
      #pragma unroll
      for (int kni = 0; kni < 4; ++kni)
        #pragma unroll
        for (int r = 0; r < 4; ++r){
          float p = __expf(acc_s[kni][qmi][r] - mnew);
          acc_s[kni][qmi][r] = p;
          ls += p;
        }
      ls += __shfl_xor(ls, 16, 64);
      ls += __shfl_xor(ls, 32, 64);
      l_run[qmi] = l_run[qmi]*ef[qmi] + ls;
      m_run[qmi] = mnew;
    }

    #pragma unroll
    for (int dj = 0; dj < 8; ++dj)
      #pragma unroll
      for (int qmi = 0; qmi < 2; ++qmi)
        #pragma unroll
        for (int r = 0; r < 4; ++r) acc_o[dj][qmi][r] *= ef[qmi];

    // pack P to bf16 pairs (k-consecutive along regs)
    u32 pk[4][2][2];
    #pragma unroll
    for (int kni = 0; kni < 4; ++kni)
      #pragma unroll
      for (int qmi = 0; qmi < 2; ++qmi){
        pk[kni][qmi][0] = (u32)f2bf(acc_s[kni][qmi][0]) | ((u32)f2bf(acc_s[kni][qmi][1]) << 16);
        pk[kni][qmi][1] = (u32)f2bf(acc_s[kni][qmi][2]) | ((u32)f2bf(acc_s[kni][qmi][3]) << 16);
      }

    const int srcA = ((l4 & 1) << 5) + l15;
    const int srcB = srcA + 16;
    const bool hi = (l4 >> 1) != 0;
    #pragma unroll
    for (int ks = 0; ks < 2; ++ks){
      bfrag vf[8];
      #pragma unroll
      for (int dj = 0; dj < 8; ++dj){
        int rd = dj*16 + l15;
        int slot = (ks*4 + l4) ^ (rd & 7);
        vf[dj] = *(const bfrag*)&Vt[cur][rd*64 + slot*8];
      }
      #pragma unroll
      for (int qmi = 0; qmi < 2; ++qmi){
        u32 a0 = (u32)__shfl((int)pk[ks*2][qmi][0], srcA, 64);
        u32 a1 = (u32)__shfl((int)pk[ks*2][qmi][1], srcA, 64);
        u32 b0 = (u32)__shfl((int)pk[ks*2][qmi][0], srcB, 64);
        u32 b1 = (u32)__shfl((int)pk[ks*2][qmi][1], srcB, 64);
        u32 c0 = (u32)__shfl((int)pk[ks*2+1][qmi][0], srcA, 64);
        u32 c1 = (u32)__shfl((int)pk[ks*2+1][qmi][1], srcA, 64);
        u32 d0 = (u32)__shfl((int)pk[ks*2+1][qmi][0], srcB, 64);
        u32 d1 = (u32)__shfl((int)pk[ks*2+1][qmi][1], srcB, 64);
        union { u32 u[4]; bfrag v; } pf;
        pf.u[0] = hi ? c0 : a0;
        pf.u[1] = hi ? c1 : a1;
        pf.u[2] = hi ? d0 : b0;
        pf.u[3] = hi ? d1 : b1;
        #pragma unroll
        for (int dj = 0; dj < 8; ++dj)
          acc_o[dj][qmi] = __builtin_amdgcn_mfma_f32_16x16x32_bf16(vf[dj], pf.v, acc_o[dj][qmi], 0, 0, 0);
      }
    }
    cur ^= 1;
  }

  #pragma unroll
  for (int qmi = 0; qmi < 2; ++qmi){
    float inv = 1.0f / l_run[qmi];
    int bn = b*1024 + qbase + qmi*16 + l15;
    u16* orow = attn_o + (size_t)bn*2048 + h*128;
    #pragma unroll
    for (int dj = 0; dj < 8; ++dj){
      u16x4 o;
      #pragma unroll
      for (int r = 0; r < 4; ++r) o[r] = f2bf(acc_o[dj][qmi][r]*inv);
      *(u16x4*)(orow + dj*16 + l4*4) = o;
    }
  }
}

// ---------------- launch ----------------
extern "C" void kernel_launch(void* const* d_in, const int* in_sizes, int n_in,
                              void* d_out, int out_size, void* d_ws, size_t ws_size,
                              hipStream_t stream)
{
  const float* x      = (const float*)d_in[0];
  const float* past_k = (const float*)d_in[1];
  const float* past_v = (const float*)d_in[2];
  const float* fcos   = (const float*)d_in[3];
  const float* fsin   = (const float*)d_in[4];
  const float* Wq     = (const float*)d_in[5];
  const float* Wk     = (const float*)d_in[6];
  const float* Wv     = (const float*)d_in[7];
  const float* Wo     = (const float*)d_in[8];
  const float* bo     = (const float*)d_in[9];
  const float* wqn    = (const float*)d_in[10];
  const float* wkn    = (const float*)d_in[11];
  float* out = (float*)d_out;
  char* ws = (char*)d_ws;

  u16* xb    = (u16*)(ws);                    // 16.8 MB
  u16* wqkv  = (u16*)(ws + 16777216);         // 12.6 MB
  u16* wo_b  = (u16*)(ws + 29360128);         // 8.4 MB
  u16* q_ro  = (u16*)(ws + 37748736);         // 16.8 MB
  u16* k_all = (u16*)(ws + 54525952);         // 16.8 MB
  u16* v_all = (u16*)(ws + 71303168);         // 16.8 MB
  u16* v_t   = (u16*)(ws + 88080384);         // 16.8 MB
  u16* proj  = (u16*)(ws + 104857600);        // 25.2 MB (attn_o aliases; proj dead by then)
  u16* attn_o = proj;

  k_cvt<<<8192, 256, 0, stream>>>(x, xb, 2097152);
  k_cvt<<<4096, 256, 0, stream>>>(Wq, wqkv, 1048576);
  k_cvt<<<1024, 256, 0, stream>>>(Wk, wqkv + 2048*2048, 262144);
  k_cvt<<<1024, 256, 0, stream>>>(Wv, wqkv + 2560*2048, 262144);
  k_cvt<<<4096, 256, 0, stream>>>(Wo, wo_b, 1048576);
  k_cvt_past<<<6144, 256, 0, stream>>>(past_k, k_all, 1572864);
  k_cvt_past<<<6144, 256, 0, stream>>>(past_v, v_all, 1572864);

  k_gemm<0><<<dim3(24, 32), 256, 0, stream>>>(xb, wqkv, proj, nullptr, nullptr, 4096, 3072, 2048);
  k_rmsrope<<<dim3(4096, 6), 256, 0, stream>>>(proj, fcos, fsin, wqn, wkn, q_ro, k_all, v_all);
  k_transpose_v<<<dim3(64, 2, 16), 256, 0, stream>>>(v_all, v_t);
  k_attn<<<256, 512, 0, stream>>>(q_ro, k_all, v_t, attn_o);
  k_gemm<1><<<dim3(16, 32), 256, 0, stream>>>(attn_o, wo_b, nullptr, out, bo, 4096, 2048, 2048);
}

// Round 2
// 257.447 us; speedup vs baseline: 1.1091x; 1.1091x over previous
//
#include <hip/hip_runtime.h>
#include <hip/hip_bf16.h>
#include <stdint.h>

typedef unsigned short u16;
typedef unsigned int u32;
typedef __attribute__((ext_vector_type(8))) __bf16 bfrag;
typedef __attribute__((ext_vector_type(4))) float f32x4;
typedef __attribute__((ext_vector_type(16))) float f32x16;
typedef __attribute__((ext_vector_type(4))) unsigned short u16x4;

__device__ __forceinline__ u16 f2bf(float f){
  union { float f; u32 u; } v; v.f = f;
  u32 u = v.u;
  return (u16)((u + 0x7fffu + ((u >> 16) & 1u)) >> 16);
}

__device__ __forceinline__ u32 cvtpk(float a, float b){
  u32 r; asm("v_cvt_pk_bf16_f32 %0, %1, %2" : "=v"(r) : "v"(a), "v"(b)); return r;
}
__device__ __forceinline__ void swap32(u32 &a, u32 &b){
  asm volatile("v_permlane32_swap_b32 %0, %1" : "+v"(a), "+v"(b));
}

__device__ __forceinline__ void gload_lds16(const void* g, void* l){
  __builtin_amdgcn_global_load_lds(
      (__attribute__((address_space(1))) void*)(unsigned long long)g,
      (__attribute__((address_space(3))) void*)(u32)(unsigned long long)l,
      16, 0, 0);
}

// ---------------- converts ----------------
__global__ void __launch_bounds__(256) k_cvt(const float* __restrict__ s, u16* __restrict__ d, int n4){
  int i = blockIdx.x*256 + threadIdx.x;
  if (i >= n4) return;
  float4 v = ((const float4*)s)[i];
  u16x4 o; o[0]=f2bf(v.x); o[1]=f2bf(v.y); o[2]=f2bf(v.z); o[3]=f2bf(v.w);
  ((u16x4*)d)[i] = o;
}

// past_k [16][3072][128] f32 -> k_all [16][4096][128] bf16 (rows 0..3071)
__global__ void __launch_bounds__(256) k_cvt_past(const float* __restrict__ s, u16* __restrict__ d, int n4){
  int i = blockIdx.x*256 + threadIdx.x;
  if (i >= n4) return;
  int e = i*4;
  int row = e >> 7;
  int col = e & 127;
  int bh = row / 3072;
  int m = row - bh*3072;
  float4 v = ((const float4*)s)[i];
  u16x4 o; o[0]=f2bf(v.x); o[1]=f2bf(v.y); o[2]=f2bf(v.z); o[3]=f2bf(v.w);
  *(u16x4*)(d + ((size_t)(bh*4096 + m) << 7) + col) = o;
}

// past_v [16][3072][128] f32 -> v_t [16][128][4096] bf16 (cols 0..3071), transposed
__global__ void __launch_bounds__(256) k_cvt_past_vt(const float* __restrict__ s, u16* __restrict__ v_t){
  __shared__ u16 T[64][65];
  const int mt = blockIdx.x, dt = blockIdx.y, pl = blockIdx.z;  // mt<48, dt<2
  const float* src = s + (size_t)pl*3072*128 + (size_t)mt*64*128 + dt*64;
  u16* dst = v_t + (size_t)pl*128*4096 + (size_t)dt*64*4096 + mt*64;
  const int t = threadIdx.x;
  #pragma unroll
  for (int r = 0; r < 2; ++r){
    int row = r*32 + (t >> 3);
    int c8 = (t & 7)*8;
    float4 va = *(const float4*)(src + (size_t)row*128 + c8);
    float4 vb = *(const float4*)(src + (size_t)row*128 + c8 + 4);
    T[row][c8+0]=f2bf(va.x); T[row][c8+1]=f2bf(va.y); T[row][c8+2]=f2bf(va.z); T[row][c8+3]=f2bf(va.w);
    T[row][c8+4]=f2bf(vb.x); T[row][c8+5]=f2bf(vb.y); T[row][c8+6]=f2bf(vb.z); T[row][c8+7]=f2bf(vb.w);
  }
  __syncthreads();
  #pragma unroll
  for (int r = 0; r < 2; ++r){
    int drow = r*32 + (t >> 3);
    int m8 = (t & 7)*8;
    union { bfrag v; u16 e[8]; } uv;
    #pragma unroll
    for (int j = 0; j < 8; ++j) uv.e[j] = T[m8 + j][drow];
    *(bfrag*)(dst + (size_t)drow*4096 + m8) = uv.v;
  }
}

// ---------------- GEMM C[M][N] = A[M][K] * B[N][K]^T ----------------
template<int EPI>
__global__ void __launch_bounds__(256) k_gemm(
    const u16* __restrict__ A, const u16* __restrict__ Bm,
    u16* __restrict__ Cb, float* __restrict__ Cf, const float* __restrict__ bias,
    int M, int Nn, int K)
{
  __shared__ u16 lsA[2][4096];
  __shared__ u16 lsB[2][4096];
  const int t = threadIdx.x, lane = t & 63, wid = t >> 6;
  const int l15 = lane & 15, l4 = lane >> 4;
  const int wm = wid >> 1, wn = wid & 1;
  const int bn = blockIdx.x, bm = blockIdx.y;
  const u16* Ab = A + (size_t)bm*128*K;
  const u16* Bb = Bm + (size_t)bn*128*K;

  auto stage = [&](u16* ls, const u16* g, int kof){
    #pragma unroll
    for (int r = 0; r < 2; ++r){
      int row = r*64 + (t >> 2);
      int s = (t & 3) ^ ((row >> 1) & 3);
      gload_lds16(g + (size_t)row*K + kof + s*8, ls + r*2048 + wid*512);
    }
  };

  f32x4 acc[4][4] = {};
  stage(&lsA[0][0], Ab, 0);
  stage(&lsB[0][0], Bb, 0);
  const int NT = K >> 5;
  const int sl = l4 ^ ((l15 >> 1) & 3);
  const int ra0 = wm*64 + l15, rb0 = wn*64 + l15;
  for (int kt = 0; kt < NT; ++kt){
    __syncthreads();
    const int cur = kt & 1;
    if (kt + 1 < NT){
      stage(&lsA[cur ^ 1][0], Ab, (kt + 1)*32);
      stage(&lsB[cur ^ 1][0], Bb, (kt + 1)*32);
    }
    bfrag af[4], bfv[4];
    #pragma unroll
    for (int i = 0; i < 4; ++i){
      af[i]  = *(const bfrag*)&lsA[cur][(ra0 + i*16)*32 + sl*8];
      bfv[i] = *(const bfrag*)&lsB[cur][(rb0 + i*16)*32 + sl*8];
    }
    #pragma unroll
    for (int i = 0; i < 4; ++i)
      #pragma unroll
      for (int j = 0; j < 4; ++j)
        acc[i][j] = __builtin_amdgcn_mfma_f32_16x16x32_bf16(af[i], bfv[j], acc[i][j], 0, 0, 0);
  }
  const int row0 = bm*128 + wm*64, col0 = bn*128 + wn*64;
  #pragma unroll
  for (int i = 0; i < 4; ++i)
    #pragma unroll
    for (int j = 0; j < 4; ++j){
      int cc = col0 + j*16 + l15;
      float bv = (EPI == 1) ? bias[cc] : 0.f;
      #pragma unroll
      for (int r = 0; r < 4; ++r){
        int rr = row0 + i*16 + l4*4 + r;
        if (EPI == 0) Cb[(size_t)rr*Nn + cc] = f2bf(acc[i][j][r]);
        else          Cf[(size_t)rr*Nn + cc] = acc[i][j][r] + bv;
      }
    }
}

// ---------------- fused RMSNorm + RoPE + scatter ----------------
__global__ void __launch_bounds__(256) k_rmsrope(
    const u16* __restrict__ proj, const float* __restrict__ cosb, const float* __restrict__ sinb,
    const float* __restrict__ wq, const float* __restrict__ wk,
    u16* __restrict__ q_ro, u16* __restrict__ k_all, u16* __restrict__ v_all)
{
  const int bn = blockIdx.x;
  const int b = bn >> 10, n = bn & 1023;
  const int lane = threadIdx.x & 63, w = threadIdx.x >> 6;
  const int chunk = blockIdx.y*4 + w;
  const u16* src = proj + (size_t)bn*3072 + chunk*128 + lane*2;
  const u32 raw = *(const u32*)src;
  union { u32 u; float f; } a, c2;
  a.u = raw << 16; c2.u = raw & 0xffff0000u;
  float x0 = a.f, x1 = c2.f;
  if (chunk >= 20){
    int hk = chunk - 20;
    *(u32*)(v_all + (((size_t)(b*4 + hk)*4096 + 3072 + n) << 7) + lane*2) = raw;
    return;
  }
  float ss = x0*x0 + x1*x1;
  #pragma unroll
  for (int m = 1; m < 64; m <<= 1) ss += __shfl_xor(ss, m, 64);
  float inv = rsqrtf(ss*(1.f/128.f) + 1e-6f);
  const float* wn2 = (chunk < 16) ? wq : wk;
  x0 *= inv*wn2[lane*2]; x1 *= inv*wn2[lane*2 + 1];
  float cz = cosb[n*64 + lane], sz = sinb[n*64 + lane];
  float r0 = x0*cz - x1*sz;
  float r1 = x0*sz + x1*cz;
  u32 outp = (u32)f2bf(r0) | ((u32)f2bf(r1) << 16);
  if (chunk < 16){
    *(u32*)(q_ro + (((size_t)(b*16 + chunk)*1024 + n) << 7) + lane*2) = outp;
  } else {
    int hk = chunk - 16;
    *(u32*)(k_all + (((size_t)(b*4 + hk)*4096 + 3072 + n) << 7) + lane*2) = outp;
  }
}

// ---------------- V transpose (new rows only): v_all[pl][m][d] -> v_t[pl][d][m] ----------------
__global__ void __launch_bounds__(256) k_transpose_v(const u16* __restrict__ v_all, u16* __restrict__ v_t){
  __shared__ u16 T[64][65];
  const int mt = blockIdx.x + 48, dt = blockIdx.y, pl = blockIdx.z;
  const u16* src = v_all + (size_t)pl*4096*128 + (size_t)mt*64*128 + dt*64;
  u16* dst = v_t + (size_t)pl*128*4096 + (size_t)dt*64*4096 + mt*64;
  const int t = threadIdx.x;
  #pragma unroll
  for (int r = 0; r < 2; ++r){
    int row = r*32 + (t >> 3);
    int c8 = (t & 7)*8;
    bfrag v = *(const bfrag*)(src + (size_t)row*128 + c8);
    union { bfrag v; u16 e[8]; } uv; uv.v = v;
    #pragma unroll
    for (int j = 0; j < 8; ++j) T[row][c8 + j] = uv.e[j];
  }
  __syncthreads();
  #pragma unroll
  for (int r = 0; r < 2; ++r){
    int drow = r*32 + (t >> 3);
    int m8 = (t & 7)*8;
    union { bfrag v; u16 e[8]; } uv;
    #pragma unroll
    for (int j = 0; j < 8; ++j) uv.e[j] = T[m8 + j][drow];
    *(bfrag*)(dst + (size_t)drow*4096 + m8) = uv.v;
  }
}

// ---------------- flash attention, 32x32 MFMA, swapped QK^T, cvt_pk+permlane ----------------
// grid 512: XCD-clustered: xcd = bid&7 owns planes [2*xcd, 2*xcd+2); 4 waves = 4 heads
__global__ void __launch_bounds__(256, 2) k_attn(
    const u16* __restrict__ q_ro, const u16* __restrict__ k_all,
    const u16* __restrict__ v_t, u16* __restrict__ attn_o)
{
  __shared__ u16 Kl[2][64*128];   // [k][d], 16B-slot ^= (row&7)
  __shared__ u16 Vt[2][128*64];   // [d][k], 16B-slot ^= (row&7)
  const int bid = blockIdx.x;
  const int xcd = bid & 7, idx = bid >> 3;
  const int plane = (xcd << 1) | (idx >> 5);
  const int qt = idx & 31;
  const int b = plane >> 2, hk = plane & 3;
  const int t = threadIdx.x, lane = t & 63, w = t >> 6;
  const int l31 = lane & 31, lh = lane >> 5;
  const int h = hk*4 + w;
  const int qbase = qt*32;

  const u16* qplane = q_ro + (size_t)(b*16 + h)*1024*128;
  const u16* kplane = k_all + (size_t)(b*4 + hk)*4096*128;
  const u16* vplane = v_t  + (size_t)(b*4 + hk)*128*4096;

  // Q frags (B operand): lane holds Q[qbase+l31][dks*16 + lh*8 + j]
  bfrag qf[8];
  {
    const u16* qrow = qplane + (size_t)(qbase + l31)*128 + lh*8;
    #pragma unroll
    for (int dks = 0; dks < 8; ++dks)
      qf[dks] = *(const bfrag*)(qrow + dks*16);
  }

  auto stage = [&](int buf, int kb){
    #pragma unroll
    for (int r = 0; r < 4; ++r){       // K: 64 rows x 128 d
      int row = r*16 + (t >> 4);
      int scol = ((t & 15) ^ (row & 7) ^ ((row & 8) ? 8 : 0) ^ ((row & 8) ? 8 : 0)) * 8; // == (slot ^ (row&7))*8
      gload_lds16(kplane + (size_t)(kb + row)*128 + (((t & 15) ^ (row & 7))*8), &Kl[buf][r*2048 + t*8]);
      (void)scol;
    }
    #pragma unroll
    for (int r = 0; r < 4; ++r){       // V^T: 128 rows(d) x 64 k
      int row = r*32 + (t >> 3);
      gload_lds16(vplane + (size_t)row*4096 + kb + (((t & 7) ^ (row & 7))*8), &Vt[buf][r*2048 + t*8]);
    }
  };

  f32x16 acc_o[4] = {};
  float m_run = -1e30f, l_run = 0.f;
  const float KL = 0.127529904f;        // (1/sqrt(128)) * log2(e)
  const int kb0 = (qbase + 1024) & ~63;
  const int qpos = 3072 + qbase + l31;

  stage(0, kb0);
  int cur = 0;
  for (int c = 0; c < 33; ++c){
    __syncthreads();
    const int kb = kb0 + c*64;
    if (c < 32) stage(cur ^ 1, kb + 64);

    // S^T[k][q] = K · Q^T   (A = K rows, B = Q^T)
    f32x16 s0 = {}, s1 = {};
    #pragma unroll
    for (int dks = 0; dks < 8; ++dks){
      const int sw = l31 & 7;
      bfrag k0 = *(const bfrag*)&Kl[cur][(l31)*128      + (((dks*2 + lh) ^ sw)*8)];
      bfrag k1 = *(const bfrag*)&Kl[cur][(32 + l31)*128 + (((dks*2 + lh) ^ sw)*8)];
      s0 = __builtin_amdgcn_mfma_f32_32x32x16_bf16(k0, qf[dks], s0, 0, 0, 0);
      s1 = __builtin_amdgcn_mfma_f32_32x32x16_bf16(k1, qf[dks], s1, 0, 0, 0);
    }

    if ((c == 0) | (c == 32)){
      #pragma unroll
      for (int r = 0; r < 16; ++r){
        int krow = (r & 3) + 8*(r >> 2) + 4*lh;
        int d0 = qpos - (kb + krow);
        int d1 = qpos - (kb + 32 + krow);
        if ((unsigned)d0 >= 2048u) s0[r] = -1e30f;
        if ((unsigned)d1 >= 2048u) s1[r] = -1e30f;
      }
    }

    float mx = s0[0];
    #pragma unroll
    for (int r = 1; r < 16; ++r) mx = fmaxf(mx, s0[r]);
    #pragma unroll
    for (int r = 0; r < 16; ++r) mx = fmaxf(mx, s1[r]);
    mx = fmaxf(mx, __shfl_xor(mx, 32, 64));

    if (__any(mx > m_run + 62.7f)){
      float mnew = fmaxf(m_run, mx);
      float ef = exp2f(KL*(m_run - mnew));
      m_run = mnew;
      l_run *= ef;
      #pragma unroll
      for (int dj = 0; dj < 4; ++dj)
        #pragma unroll
        for (int r = 0; r < 16; ++r) acc_o[dj][r] *= ef;
    }
    const float nKm = -KL*m_run;
    float ls = 0.f;
    #pragma unroll
    for (int r = 0; r < 16; ++r){ float p = exp2f(fmaf(KL, s0[r], nKm)); s0[r] = p; ls += p; }
    #pragma unroll
    for (int r = 0; r < 16; ++r){ float p = exp2f(fmaf(KL, s1[r], nKm)); s1[r] = p; ls += p; }
    l_run += ls;

    // P^T B-frags via cvt_pk + permlane32_swap (k in frag f covers f*16..f*16+15)
    union { u32 u[4]; bfrag v; } pfrag[4];
    {
      u32 a0 = cvtpk(s0[0],  s0[1]),  a1 = cvtpk(s0[2],  s0[3]);
      u32 b0 = cvtpk(s0[4],  s0[5]),  b1 = cvtpk(s0[6],  s0[7]);
      swap32(a0, b0); swap32(a1, b1);
      pfrag[0].u[0]=a0; pfrag[0].u[1]=a1; pfrag[0].u[2]=b0; pfrag[0].u[3]=b1;
      u32 c0 = cvtpk(s0[8],  s0[9]),  c1 = cvtpk(s0[10], s0[11]);
      u32 e0 = cvtpk(s0[12], s0[13]), e1 = cvtpk(s0[14], s0[15]);
      swap32(c0, e0); swap32(c1, e1);
      pfrag[1].u[0]=c0; pfrag[1].u[1]=c1; pfrag[1].u[2]=e0; pfrag[1].u[3]=e1;
    }
    {
      u32 a0 = cvtpk(s1[0],  s1[1]),  a1 = cvtpk(s1[2],  s1[3]);
      u32 b0 = cvtpk(s1[4],  s1[5]),  b1 = cvtpk(s1[6],  s1[7]);
      swap32(a0, b0); swap32(a1, b1);
      pfrag[2].u[0]=a0; pfrag[2].u[1]=a1; pfrag[2].u[2]=b0; pfrag[2].u[3]=b1;
      u32 c0 = cvtpk(s1[8],  s1[9]),  c1 = cvtpk(s1[10], s1[11]);
      u32 e0 = cvtpk(s1[12], s1[13]), e1 = cvtpk(s1[14], s1[15]);
      swap32(c0, e0); swap32(c1, e1);
      pfrag[3].u[0]=c0; pfrag[3].u[1]=c1; pfrag[3].u[2]=e0; pfrag[3].u[3]=e1;
    }

    // O^T[d][q] += V^T · P^T
    #pragma unroll
    for (int ks = 0; ks < 4; ++ks)
      #pragma unroll
      for (int dj = 0; dj < 4; ++dj){
        int row = dj*32 + l31;
        bfrag vf = *(const bfrag*)&Vt[cur][row*64 + (((ks*2 + lh) ^ (row & 7))*8)];
        acc_o[dj] = __builtin_amdgcn_mfma_f32_32x32x16_bf16(vf, pfrag[ks].v, acc_o[dj], 0, 0, 0);
      }
    cur ^= 1;
  }

  float lt = l_run + __shfl_xor(l_run, 32, 64);
  float inv = 1.0f / lt;
  const int bn = b*1024 + qbase + l31;
  u16* orow = attn_o + (size_t)bn*2048 + h*128;
  #pragma unroll
  for (int dj = 0; dj < 4; ++dj)
    #pragma unroll
    for (int rg = 0; rg < 4; ++rg){
      int d0 = dj*32 + rg*8 + 4*lh;
      u16x4 o;
      #pragma unroll
      for (int r2 = 0; r2 < 4; ++r2) o[r2] = f2bf(acc_o[dj][rg*4 + r2]*inv);
      *(u16x4*)(orow + d0) = o;
    }
}

// ---------------- launch ----------------
extern "C" void kernel_launch(void* const* d_in, const int* in_sizes, int n_in,
                              void* d_out, int out_size, void* d_ws, size_t ws_size,
                              hipStream_t stream)
{
  const float* x      = (const float*)d_in[0];
  const float* past_k = (const float*)d_in[1];
  const float* past_v = (const float*)d_in[2];
  const float* fcos   = (const float*)d_in[3];
  const float* fsin   = (const float*)d_in[4];
  const float* Wq     = (const float*)d_in[5];
  const float* Wk     = (const float*)d_in[6];
  const float* Wv     = (const float*)d_in[7];
  const float* Wo     = (const float*)d_in[8];
  const float* bo     = (const float*)d_in[9];
  const float* wqn    = (const float*)d_in[10];
  const float* wkn    = (const float*)d_in[11];
  float* out = (float*)d_out;
  char* ws = (char*)d_ws;

  u16* xb    = (u16*)(ws);
  u16* wqkv  = (u16*)(ws + 16777216);
  u16* wo_b  = (u16*)(ws + 29360128);
  u16* q_ro  = (u16*)(ws + 37748736);
  u16* k_all = (u16*)(ws + 54525952);
  u16* v_all = (u16*)(ws + 71303168);
  u16* v_t   = (u16*)(ws + 88080384);
  u16* proj  = (u16*)(ws + 104857600);
  u16* attn_o = proj;

  k_cvt<<<8192, 256, 0, stream>>>(x, xb, 2097152);
  k_cvt<<<4096, 256, 0, stream>>>(Wq, wqkv, 1048576);
  k_cvt<<<1024, 256, 0, stream>>>(Wk, wqkv + 2048*2048, 262144);
  k_cvt<<<1024, 256, 0, stream>>>(Wv, wqkv + 2560*2048, 262144);
  k_cvt<<<4096, 256, 0, stream>>>(Wo, wo_b, 1048576);
  k_cvt_past<<<6144, 256, 0, stream>>>(past_k, k_all, 1572864);
  k_cvt_past_vt<<<dim3(48, 2, 16), 256, 0, stream>>>(past_v, v_t);

  k_gemm<0><<<dim3(24, 32), 256, 0, stream>>>(xb, wqkv, proj, nullptr, nullptr, 4096, 3072, 2048);
  k_rmsrope<<<dim3(4096, 6), 256, 0, stream>>>(proj, fcos, fsin, wqn, wkn, q_ro, k_all, v_all);
  k_transpose_v<<<dim3(16, 2, 16), 256, 0, stream>>>(v_all, v_t);
  k_attn<<<512, 256, 0, stream>>>(q_ro, k_all, v_t, attn_o);
  k_gemm<1><<<dim3(16, 32), 256, 0, stream>>>(attn_o, wo_b, nullptr, out, bo, 4096, 2048, 2048);
}